// Round 12
// baseline (92.085 us; speedup 1.0000x reference)
//
#include <hip/hip_runtime.h>
#include <math.h>

// TopK router: logits = x @ W^T + bias; top-2; softmax over the 2; scatter.
// x: [N=16384, H=4096] fp32, W: [E=64, H=4096] fp32, bias: [64] fp32.
// d_out: [N*64] final (fp32) then [N*2] selected_experts written as floats.
//
// Round 12 = round 11 (fragment-major 1KB W regions staged via
// global_load_lds width=16; conflict-free contiguous ds_read_b128; counted
// vmcnt + raw barrier) with the round-11 bug fixed: XLOADM(p+2) had been
// moved BEFORE split3_8 but overwrites the same xA*/xB* registers the split
// was about to consume (WAR at source level -> every phase used the wrong
// X chunk -> garbage logits). Order restored: split first, prefetch after
// (round 10's proven dataflow). Plus sched_barrier(0) after STAGE pins the
// 6 gload_lds as oldest vmem so vmcnt(4) drains exactly the stage; prologue
// drains vmcnt(0) once. Numerics byte-identical to passing rounds 5-10.

constexpr int E_EXPERTS = 64;
constexpr int H_DIM = 4096;
constexpr int BLOCK = 512;    // 8 waves = 4 kq-slices x 2 row-halves
constexpr int ROWS_B = 64;    // rows per block
constexpr int NPH = 32;       // phases; 32 k per kq-slice per phase
constexpr int KSLICE = 1024;  // k per kq slice
constexpr int REG_SH = 512;   // shorts per staged region (1 KB)
constexpr int BUFS = 48 * REG_SH;  // 24576 shorts = 48 KB per buffer
constexpr int W_ELEMS = E_EXPERTS * H_DIM;

typedef __attribute__((ext_vector_type(8))) short short8;
typedef __attribute__((ext_vector_type(4))) float f32x4;

__device__ __forceinline__ float4 ld4(const float* p) {
  return *reinterpret_cast<const float4*>(p);
}

// Async global->LDS, 16B per lane: per-lane GLOBAL src, wave-uniform linear
// LDS dest (HW writes base + lane*16). Tracked by vmcnt.
__device__ __forceinline__ void gload16(const unsigned short* g,
                                        unsigned short* l) {
  __builtin_amdgcn_global_load_lds(
      (const __attribute__((address_space(1))) void*)g,
      (__attribute__((address_space(3))) void*)l, 16, 0, 0);
}

__device__ __forceinline__ unsigned short bf_rne(float x) {
  unsigned u = __builtin_bit_cast(unsigned, x);
  return (unsigned short)((u + 0x7fffu + ((u >> 16) & 1u)) >> 16);
}
__device__ __forceinline__ float bf2f(unsigned short b) {
  return __builtin_bit_cast(float, ((unsigned)b) << 16);
}
// x = h + m + l + err, |err| <= 2^-25 |x|. (h,m trunc; l RNE; residuals exact)
__device__ __forceinline__ void split3(float x, unsigned short& h,
                                       unsigned short& m, unsigned short& l) {
  unsigned short hb = (unsigned short)(__builtin_bit_cast(unsigned, x) >> 16);
  float r1 = x - bf2f(hb);
  unsigned short mb = (unsigned short)(__builtin_bit_cast(unsigned, r1) >> 16);
  float r2 = r1 - bf2f(mb);
  h = hb;
  m = mb;
  l = bf_rne(r2);
}
__device__ __forceinline__ void split3_8(float4 a, float4 b, short8& h,
                                         short8& m, short8& l) {
  unsigned short hh, mm, ll;
  split3(a.x, hh, mm, ll); h[0] = (short)hh; m[0] = (short)mm; l[0] = (short)ll;
  split3(a.y, hh, mm, ll); h[1] = (short)hh; m[1] = (short)mm; l[1] = (short)ll;
  split3(a.z, hh, mm, ll); h[2] = (short)hh; m[2] = (short)mm; l[2] = (short)ll;
  split3(a.w, hh, mm, ll); h[3] = (short)hh; m[3] = (short)mm; l[3] = (short)ll;
  split3(b.x, hh, mm, ll); h[4] = (short)hh; m[4] = (short)mm; l[4] = (short)ll;
  split3(b.y, hh, mm, ll); h[5] = (short)hh; m[5] = (short)mm; l[5] = (short)ll;
  split3(b.z, hh, mm, ll); h[6] = (short)hh; m[6] = (short)mm; l[6] = (short)ll;
  split3(b.w, hh, mm, ll); h[7] = (short)hh; m[7] = (short)mm; l[7] = (short)ll;
}

// Pre-kernel: split W into h/m/l bf16 planes (same math as split3).
__global__ __launch_bounds__(256) void split_w_kernel(
    const float* __restrict__ w, unsigned short* __restrict__ wh,
    unsigned short* __restrict__ wm, unsigned short* __restrict__ wl) {
  const int i = (blockIdx.x * 256 + threadIdx.x) * 4;
  float4 v = ld4(w + i);
  ushort4 h4, m4, l4;
  split3(v.x, h4.x, m4.x, l4.x);
  split3(v.y, h4.y, m4.y, l4.y);
  split3(v.z, h4.z, m4.z, l4.z);
  split3(v.w, h4.w, m4.w, l4.w);
  *reinterpret_cast<ushort4*>(wh + i) = h4;
  *reinterpret_cast<ushort4*>(wm + i) = m4;
  *reinterpret_cast<ushort4*>(wl + i) = l4;
}

__global__ __launch_bounds__(BLOCK, 1) void topk_router_mfma(
    const float* __restrict__ x, const unsigned short* __restrict__ wh,
    const unsigned short* __restrict__ wm,
    const unsigned short* __restrict__ wl, const float* __restrict__ bias,
    float* __restrict__ out_final, float* __restrict__ out_idx) {
  __shared__ unsigned short smem_s[2 * BUFS];  // 98304 B; fp32 partials alias

  const int tid = threadIdx.x;
  const int lane = tid & 63;
  const int wid = tid >> 6;
  const int kq = wid & 3;   // K slice (1024 k)
  const int rh = wid >> 2;  // row half (32 rows)
  const int rowBase = blockIdx.x * ROWS_B;
  const int lr = lane & 15;
  const int kg = lane >> 4;

  // Staging: 48 regions (kq,pl,eg) of 1 KB; wave w stages r = 6w+i, i=0..5.
  // Region r: kq=r/12, pl=(r%12)>>2, eg=r&3. Lane ll holds
  // W_pl[eg*16 + (ll&15)][kq*1024 + t*32 + (ll>>4)*8 ..+8) at slot ll*16B.
#define DECL_RG(i)                                                       \
  const int r##i = wid * 6 + (i);                                        \
  const int q##i = r##i >> 2;                                            \
  const int rkq##i = q##i / 3;                                           \
  const int rpl##i = q##i - rkq##i * 3;                                  \
  const unsigned short* gb##i =                                          \
      (rpl##i == 0 ? wh : (rpl##i == 1 ? wm : wl)) +                     \
      (size_t)((r##i & 3) * 16 + lr) * H_DIM + rkq##i * KSLICE + kg * 8; \
  unsigned short* lb##i = &smem_s[r##i * REG_SH];
  DECL_RG(0) DECL_RG(1) DECL_RG(2) DECL_RG(3) DECL_RG(4) DECL_RG(5)

#define STAGE(t, buf)                                  \
  do {                                                 \
    gload16(gb0 + (size_t)(t) * 32, lb0 + (buf)*BUFS); \
    gload16(gb1 + (size_t)(t) * 32, lb1 + (buf)*BUFS); \
    gload16(gb2 + (size_t)(t) * 32, lb2 + (buf)*BUFS); \
    gload16(gb3 + (size_t)(t) * 32, lb3 + (buf)*BUFS); \
    gload16(gb4 + (size_t)(t) * 32, lb4 + (buf)*BUFS); \
    gload16(gb5 + (size_t)(t) * 32, lb5 + (buf)*BUFS); \
  } while (0)

  // X: this wave's 32 rows (2 A-frags) x its 1024-k slice.
  const float* __restrict__ xr0 =
      x + (size_t)(rowBase + rh * 32 + lr) * H_DIM + kq * KSLICE + kg * 8;
  const float* __restrict__ xr1 = xr0 + (size_t)16 * H_DIM;

  float4 xA0, xA1, xA2, xA3, xB0, xB1, xB2, xB3;
#define XLOADA(t)                          \
  do {                                     \
    xA0 = ld4(xr0 + (size_t)(t) * 32);     \
    xA1 = ld4(xr0 + (size_t)(t) * 32 + 4); \
    xA2 = ld4(xr1 + (size_t)(t) * 32);     \
    xA3 = ld4(xr1 + (size_t)(t) * 32 + 4); \
  } while (0)
#define XLOADB(t)                          \
  do {                                     \
    xB0 = ld4(xr0 + (size_t)(t) * 32);     \
    xB1 = ld4(xr0 + (size_t)(t) * 32 + 4); \
    xB2 = ld4(xr1 + (size_t)(t) * 32);     \
    xB3 = ld4(xr1 + (size_t)(t) * 32 + 4); \
  } while (0)

  f32x4 accA0 = {0.f, 0.f, 0.f, 0.f}, accA1 = accA0, accA2 = accA0,
        accA3 = accA0, accB0 = accA0, accB1 = accA0, accB2 = accA0,
        accB3 = accA0;

  // Prologue: stage tile0 -> buf0; X phases 0,1 -> regs; full drain once.
  STAGE(0, 0);
  __builtin_amdgcn_sched_barrier(0);
  XLOADA(0);
  XLOADB(1);
  asm volatile("s_waitcnt vmcnt(0)" ::: "memory");
  __builtin_amdgcn_s_barrier();
  __builtin_amdgcn_sched_barrier(0);

  // Consumer: contiguous 1KB per (eg,pl) region, slot = lane*16B.
#define FRAG(buf, eg, pl)                                                  \
  (*reinterpret_cast<const short8*>(                                       \
      &smem_s[(size_t)(buf)*BUFS + ((kq * 3 + (pl)) * 4 + (eg)) * REG_SH + \
              lane * 8]))

#define MM(d, a, b) d = __builtin_amdgcn_mfma_f32_16x16x32_bf16(a, b, d, 0, 0, 0)
#define PROD6(d, Ah, Am, Al, Bh, Bm, Bl)                      \
  MM(d, Ah, Bh); MM(d, Ah, Bm); MM(d, Am, Bh); MM(d, Am, Bm); \
  MM(d, Ah, Bl); MM(d, Al, Bh)

#define PHASE(p, buf, X0, X1, X2, X3, XLOADM)                           \
  do {                                                                  \
    if ((p) + 1 < NPH) STAGE((p) + 1, (buf) ^ 1); /* async, counted */  \
    __builtin_amdgcn_sched_barrier(0); /* stage = oldest vmem ops */    \
    short8 b0h = FRAG(buf, 0, 0), b0m = FRAG(buf, 0, 1),                \
           b0l = FRAG(buf, 0, 2);                                       \
    short8 b1h = FRAG(buf, 1, 0), b1m = FRAG(buf, 1, 1),                \
           b1l = FRAG(buf, 1, 2);                                       \
    short8 b2h = FRAG(buf, 2, 0), b2m = FRAG(buf, 2, 1),                \
           b2l = FRAG(buf, 2, 2);                                       \
    short8 b3h = FRAG(buf, 3, 0), b3m = FRAG(buf, 3, 1),                \
           b3l = FRAG(buf, 3, 2);                                       \
    short8 ah0, am0, al0, ah1, am1, al1;                                \
    split3_8(X0, X1, ah0, am0, al0); /* consume X(p) FIRST */           \
    split3_8(X2, X3, ah1, am1, al1);                                    \
    if ((p) + 2 < NPH) XLOADM((p) + 2); /* THEN prefetch into X regs */ \
    PROD6(accA0, ah0, am0, al0, b0h, b0m, b0l);                         \
    PROD6(accA1, ah0, am0, al0, b1h, b1m, b1l);                         \
    PROD6(accA2, ah0, am0, al0, b2h, b2m, b2l);                         \
    PROD6(accA3, ah0, am0, al0, b3h, b3m, b3l);                         \
    PROD6(accB0, ah1, am1, al1, b0h, b0m, b0l);                         \
    PROD6(accB1, ah1, am1, al1, b1h, b1m, b1l);                         \
    PROD6(accB2, ah1, am1, al1, b2h, b2m, b2l);                         \
    PROD6(accB3, ah1, am1, al1, b3h, b3m, b3l);                         \
    if ((p) + 2 < NPH) {                                                \
      asm volatile("s_waitcnt vmcnt(4)" ::: "memory"); /* stage done */ \
    } else {                                                            \
      asm volatile("s_waitcnt vmcnt(0)" ::: "memory"); /* tail drain */ \
    }                                                                   \
    __builtin_amdgcn_s_barrier();                                       \
    __builtin_amdgcn_sched_barrier(0);                                  \
  } while (0)

  for (int p = 0; p < NPH; p += 2) {
    PHASE(p, 0, xA0, xA1, xA2, xA3, XLOADA);
    PHASE(p + 1, 1, xB0, xB1, xB2, xB3, XLOADB);
  }

  // Partials: part[kq][row][e], row pad 68 floats (69632 B, aliased; loop
  // ended with vmcnt(0)+barrier so all stage ops and reads are done).
  float* part = reinterpret_cast<float*>(smem_s);
  const int pr = kg * 4;
  const int rwA = rh * 32 + pr;       // frag0 rows
  const int rwB = rh * 32 + 16 + pr;  // frag1 rows
#define PSTORE(A, rw, g)                                        \
  part[(size_t)(kq * 64 + (rw) + 0) * 68 + (g)*16 + lr] = A[0]; \
  part[(size_t)(kq * 64 + (rw) + 1) * 68 + (g)*16 + lr] = A[1]; \
  part[(size_t)(kq * 64 + (rw) + 2) * 68 + (g)*16 + lr] = A[2]; \
  part[(size_t)(kq * 64 + (rw) + 3) * 68 + (g)*16 + lr] = A[3];
  PSTORE(accA0, rwA, 0)
  PSTORE(accA1, rwA, 1)
  PSTORE(accA2, rwA, 2)
  PSTORE(accA3, rwA, 3)
  PSTORE(accB0, rwB, 0)
  PSTORE(accB1, rwB, 1)
  PSTORE(accB2, rwB, 2)
  PSTORE(accB3, rwB, 3)
  asm volatile("s_waitcnt lgkmcnt(0)" ::: "memory");
  __builtin_amdgcn_s_barrier();

  // Epilogue: 8 threads/row, 8 experts each; ordered 4-way partial sum,
  // stable top-2 scan, shfl_xor merge, softmax, scatter.
  const int r = tid >> 3;
  const int eb = (tid & 7) * 8;
  const int n = rowBase + r;

  float v8[8];
#pragma unroll
  for (int j = 0; j < 8; ++j) {
    int e = eb + j;
    v8[j] = ((part[(size_t)(0 * 64 + r) * 68 + e] +
              part[(size_t)(1 * 64 + r) * 68 + e]) +
             (part[(size_t)(2 * 64 + r) * 68 + e] +
              part[(size_t)(3 * 64 + r) * 68 + e])) +
            bias[e];
  }

  float av = -INFINITY, bv = -INFINITY;
  int ai = E_EXPERTS, bi = E_EXPERTS;
#pragma unroll
  for (int j = 0; j < 8; ++j) {
    int e = eb + j;
    float v = v8[j];
    bool beats_a = (v > av) || (v == av && e < ai);
    bool beats_b = (v > bv) || (v == bv && e < bi);
    if (beats_a) {
      bv = av; bi = ai; av = v; ai = e;
    } else if (beats_b) {
      bv = v; bi = e;
    }
  }
#pragma unroll
  for (int d = 1; d < 8; d <<= 1) {
    float av2 = __shfl_xor(av, d);
    float bv2 = __shfl_xor(bv, d);
    int ai2 = __shfl_xor(ai, d);
    int bi2 = __shfl_xor(bi, d);
    bool afirst = (av > av2) || (av == av2 && ai < ai2);
    float na, nb;
    int nai, nbi;
    if (afirst) {
      na = av; nai = ai;
      bool t = (bv > av2) || (bv == av2 && bi < ai2);
      nb = t ? bv : av2;
      nbi = t ? bi : ai2;
    } else {
      na = av2; nai = ai2;
      bool t = (av > bv2) || (av == bv2 && ai < bi2);
      nb = t ? av : bv2;
      nbi = t ? ai : bi2;
    }
    av = na; ai = nai; bv = nb; bi = nbi;
  }

  float e1 = expf(bv - av);
  float denom = 1.0f + e1;
  float p0 = 1.0f / denom;
  float p1 = e1 / denom;

#pragma unroll
  for (int i = 0; i < 2; ++i) {
    float4 o4;
    float* po = &o4.x;
#pragma unroll
    for (int j = 0; j < 4; ++j) {
      int e = eb + i * 4 + j;
      po[j] = (e == ai) ? p0 : (e == bi) ? p1 : 0.0f;
    }
    *reinterpret_cast<float4*>(&out_final[(size_t)n * E_EXPERTS + eb + i * 4]) =
        o4;
  }
  if ((tid & 7) == 0) {
    out_idx[(size_t)n * 2 + 0] = (float)ai;
    out_idx[(size_t)n * 2 + 1] = (float)bi;
  }
}

extern "C" void kernel_launch(void* const* d_in, const int* in_sizes, int n_in,
                              void* d_out, int out_size, void* d_ws,
                              size_t ws_size, hipStream_t stream) {
  const float* x = (const float*)d_in[0];
  const float* w = (const float*)d_in[1];
  const float* bias = (const float*)d_in[2];
  const int N = in_sizes[0] / H_DIM;  // 16384
  float* out_final = (float*)d_out;
  float* out_idx = out_final + (size_t)N * E_EXPERTS;

  unsigned short* wh = (unsigned short*)d_ws;  // 3 planes x 512 KB
  unsigned short* wm = wh + W_ELEMS;
  unsigned short* wl = wm + W_ELEMS;

  split_w_kernel<<<W_ELEMS / (256 * 4), 256, 0, stream>>>(w, wh, wm, wl);
  topk_router_mfma<<<N / ROWS_B, BLOCK, 0, stream>>>(x, wh, wm, wl, bias,
                                                     out_final, out_idx);
}